// Round 17
// baseline (255.629 us; speedup 1.0000x reference)
//
#include <hip/hip_runtime.h>

#define NN 100000
#define NE 1600000
#define EPSV 1e-5f

#define NBUK 196       // buckets of 512 nodes: bucket = dst >> 9
#define TILE 2048      // edges per k_bin tile
#define NTIL 782       // ceil(NE / TILE); last tile has 512 edges
#define NPREP 6250     // x-conversion blocks (6250*1024 floats = 6.4M)
#define CAP  9216      // per-bucket capacity (mean 8163, sigma ~90 -> +11 sigma)

typedef __attribute__((ext_vector_type(8))) short bf16x8;
typedef __attribute__((ext_vector_type(4))) float f32x4;

__device__ inline unsigned short f2bf(float f) {
  unsigned u = __builtin_bit_cast(unsigned, f);
  unsigned r = u + 0x7FFFu + ((u >> 16) & 1u);
  return (unsigned short)(r >> 16);
}
__device__ inline float bf2f(unsigned short s) {
  unsigned u = ((unsigned)s) << 16;
  return __builtin_bit_cast(float, u);
}

// async global->LDS, 16B per lane; LDS dest = wave-uniform base + lane*16
__device__ __forceinline__ void gload_lds16(const unsigned short* g, unsigned short* l) {
  __builtin_amdgcn_global_load_lds(
      (const __attribute__((address_space(1))) void*)g,
      (__attribute__((address_space(3))) void*)l, 16, 0, 0);
}

// ---------------- phase 1 (merged): blocks<NTIL = tile bucket-sort; rest = prep ----------------
__global__ __launch_bounds__(256) void k_binprep(const int* __restrict__ src,
                                                 const int* __restrict__ dst,
                                                 unsigned* __restrict__ pairs,
                                                 int* __restrict__ tileCnt,
                                                 int* __restrict__ tileLo,
                                                 const float* __restrict__ x,
                                                 unsigned short* __restrict__ xb,
                                                 const float* __restrict__ w1l,
                                                 const float* __restrict__ w1r,
                                                 const float* __restrict__ w2l,
                                                 const float* __restrict__ w2r,
                                                 const float* __restrict__ b1l,
                                                 const float* __restrict__ g1,
                                                 const float* __restrict__ be1,
                                                 const float* __restrict__ m1,
                                                 const float* __restrict__ v1,
                                                 const float* __restrict__ b2l,
                                                 const float* __restrict__ g2,
                                                 const float* __restrict__ be2,
                                                 const float* __restrict__ m2,
                                                 const float* __restrict__ v2,
                                                 unsigned short* __restrict__ w1c,
                                                 unsigned short* __restrict__ w2c,
                                                 float* __restrict__ bn) {
  const int tid = threadIdx.x;
  if (blockIdx.x >= NTIL) {
    const int pb = blockIdx.x - NTIL;
    const int gi = pb * 256 + tid;
    float4 v = *(const float4*)(x + (size_t)gi * 4);
    ushort4 o;
    o.x = f2bf(v.x); o.y = f2bf(v.y); o.z = f2bf(v.z); o.w = f2bf(v.w);
    *(ushort4*)(xb + (size_t)gi * 4) = o;
    if (pb < 64) {
      int i = pb * 256 + tid;  // 0..16383
      int oo = i >> 7, k = i & 127;
      float vv1 = (k < 64) ? w1l[oo * 64 + k] : w1r[oo * 64 + (k - 64)];
      w1c[i] = f2bf(vv1);
      float vv2 = (oo < 64) ? w2l[oo * 128 + k] : w2r[(oo - 64) * 128 + k];
      w2c[i] = f2bf(vv2);
      if (i < 128) {
        float sc = g1[i] * rsqrtf(v1[i] + EPSV);
        bn[i] = sc;
        bn[128 + i] = (b1l[i] - m1[i]) * sc + be1[i];
      }
      if (i < 64) {
        float sc = g2[i] * rsqrtf(v2[i] + EPSV);
        bn[256 + i] = sc;
        bn[320 + i] = (b2l[i] - m2[i]) * sc + be2[i];
      }
    }
    return;
  }
  __shared__ int cnt[NBUK];
  __shared__ int lo[NBUK];
  __shared__ int ts[256];
  __shared__ unsigned stage[TILE];
  const int t = blockIdx.x;
  const int e0 = t * TILE;
  const int m = min(TILE, NE - e0);

  int dreg[8], sreg[8];
#pragma unroll
  for (int u = 0; u < 8; ++u) {
    int i = u * 256 + tid;
    if (i < m) {
      dreg[u] = dst[e0 + i];
      sreg[u] = src[e0 + i];
    } else {
      dreg[u] = -1;
    }
  }

  for (int i = tid; i < NBUK; i += 256) cnt[i] = 0;
  __syncthreads();
#pragma unroll
  for (int u = 0; u < 8; ++u) {
    if (dreg[u] >= 0) atomicAdd(&cnt[dreg[u] >> 9], 1);
  }
  __syncthreads();
  int c = (tid < NBUK) ? cnt[tid] : 0;
  ts[tid] = c;
  __syncthreads();
  for (int d = 1; d < 256; d <<= 1) {
    int v = (tid >= d) ? ts[tid - d] : 0;
    __syncthreads();
    ts[tid] += v;
    __syncthreads();
  }
  if (tid < NBUK) {
    int ex = ts[tid] - c;
    lo[tid] = ex;
    cnt[tid] = ex;
  }
  __syncthreads();
#pragma unroll
  for (int u = 0; u < 8; ++u) {
    if (dreg[u] >= 0) {
      int pos = atomicAdd(&cnt[dreg[u] >> 9], 1);
      stage[pos] = ((unsigned)(dreg[u] & 511) << 17) | (unsigned)sreg[u];
    }
  }
  __syncthreads();
  for (int i = tid; i < m; i += 256) pairs[(size_t)t * TILE + i] = stage[i];
  if (tid < NBUK) {
    tileCnt[t * NBUK + tid] = cnt[tid] - lo[tid];
    tileLo[t * NBUK + tid] = lo[tid];
  }
}

// ---------------- phase 1.5: per-bucket prefix over tiles ----------------
__global__ __launch_bounds__(256) void k_colscan(const int* __restrict__ tileCnt,
                                                 int* __restrict__ colBase) {
  __shared__ int ts[256];
  const int tid = threadIdx.x;
  const int b = blockIdx.x;
  int v[4];
  int s = 0;
#pragma unroll
  for (int j = 0; j < 4; ++j) {
    int tt = tid * 4 + j;
    v[j] = (tt < NTIL) ? tileCnt[tt * NBUK + b] : 0;
    s += v[j];
  }
  ts[tid] = s;
  __syncthreads();
  for (int d = 1; d < 256; d <<= 1) {
    int x = (tid >= d) ? ts[tid - d] : 0;
    __syncthreads();
    ts[tid] += x;
    __syncthreads();
  }
  int run = ts[tid] - s;
#pragma unroll
  for (int j = 0; j < 4; ++j) {
    int tt = tid * 4 + j;
    if (tt < NTIL) colBase[(size_t)b * NTIL + tt] = run;
    run += v[j];
  }
}

// ---------------- phase 2: per-bucket CSR build via GATHER + degree histogram ----------------
__global__ __launch_bounds__(512) void k_build(const unsigned* __restrict__ pairs,
                                               const int* __restrict__ tileCnt,
                                               const int* __restrict__ tileLo,
                                               const int* __restrict__ colBase,
                                               int* __restrict__ deg,
                                               int* __restrict__ offset,
                                               int* __restrict__ csr,
                                               int* __restrict__ bdh) {
  __shared__ unsigned stageA[CAP];
  __shared__ unsigned stageB[CAP];
  __shared__ int colB[NTIL];
  __shared__ int tLo[NTIL];
  __shared__ int hist[512];
  __shared__ int ts[512];
  __shared__ int dh[64];
  __shared__ int obase_sh, count_sh;
  const int tid = threadIdx.x;
  const int b = blockIdx.x;
  const int nbase = b * 512;
  const int nloc = min(512, NN - nbase);

  int tb = 0;
  if (tid < NBUK) {
    int cb = colBase[(size_t)tid * NTIL + (NTIL - 1)];
    int tc = tileCnt[(NTIL - 1) * NBUK + tid];
    tb = min(cb + tc, CAP);
  }
  ts[tid] = tb;
  if (tid < 64) dh[tid] = 0;
  __syncthreads();
  for (int d = 1; d < 512; d <<= 1) {
    int v = (tid >= d) ? ts[tid - d] : 0;
    __syncthreads();
    ts[tid] += v;
    __syncthreads();
  }
  if (tid == b) { obase_sh = ts[tid] - tb; count_sh = tb; }
  for (int i = tid; i < NTIL; i += 512) {
    colB[i] = colBase[(size_t)b * NTIL + i];
    tLo[i] = tileLo[i * NBUK + b];
  }
  hist[tid] = 0;
  __syncthreads();
  const int obase = obase_sh;
  const int count = count_sh;

  for (int i = tid; i < count; i += 512) {
    int a = 0, z = NTIL - 1;
    while (a < z) {
      int mid = (a + z + 1) >> 1;
      if (colB[mid] <= i) a = mid; else z = mid - 1;
    }
    stageA[i] = pairs[(size_t)a * TILE + tLo[a] + (i - colB[a])];
  }
  __syncthreads();
  for (int i = tid; i < count; i += 512) {
    atomicAdd(&hist[stageA[i] >> 17], 1);
  }
  __syncthreads();
  int s = hist[tid];
  ts[tid] = s;
  __syncthreads();
  for (int d = 1; d < 512; d <<= 1) {
    int v = (tid >= d) ? ts[tid - d] : 0;
    __syncthreads();
    ts[tid] += v;
    __syncthreads();
  }
  int ex = ts[tid] - s;
  if (tid < nloc) {
    deg[nbase + tid] = s;
    offset[nbase + tid] = obase + ex;
    atomicAdd(&dh[min(s, 63)], 1);
  }
  hist[tid] = ex;
  __syncthreads();
  if (tid < 64) bdh[b * 64 + tid] = dh[tid];
  for (int i = tid; i < count; i += 512) {
    unsigned e = stageA[i];
    int pos = atomicAdd(&hist[e >> 17], 1);
    stageB[pos] = e & 0x1FFFFu;
  }
  __syncthreads();
  for (int i = tid; i < count; i += 512) csr[obase + i] = (int)stageB[i];
}

// ---------------- phase 2.5: degree-grouped node permutation (counting sort) ----------------
__global__ __launch_bounds__(512) void k_perm(const int* __restrict__ bdh,
                                              const int* __restrict__ deg,
                                              int* __restrict__ perm) {
  __shared__ int h[NBUK * 64];   // 50,176 B
  __shared__ int cur[64];
  const int tid = threadIdx.x;
  const int b = blockIdx.x;
  for (int i = tid; i < NBUK * 64; i += 512) h[i] = bdh[i];
  __syncthreads();
  if (tid < 64) {
    // bin total across buckets + exclusive bin base (serial over bins is fine: 64)
    int binBase = 0;
    for (int d = 0; d < 64; ++d) {
      if (d == tid) break;
      int tot = 0;
      for (int bb = 0; bb < NBUK; ++bb) tot += h[bb * 64 + d];
      binBase += tot;
    }
    // row offset: nodes of my bin in earlier buckets
    int ro = 0;
    for (int bb = 0; bb < b; ++bb) ro += h[bb * 64 + tid];
    cur[tid] = binBase + ro;
  }
  __syncthreads();
  const int node = b * 512 + tid;
  if (node < NN) {
    int bin = min(deg[node], 63);
    int pos = atomicAdd(&cur[bin], 1);
    perm[pos] = node;
  }
}

// ---------------- mean-aggregate: 8 lanes/node, degree-grouped via perm ----------------
__global__ __launch_bounds__(256) void k_aggregate(const unsigned short* __restrict__ xb,
                                                   const int* __restrict__ deg,
                                                   const int* __restrict__ offset,
                                                   const int* __restrict__ csr,
                                                   const int* __restrict__ perm,
                                                   unsigned short* __restrict__ aggB) {
  int tid = threadIdx.x;
  int node = perm[blockIdx.x * 32 + (tid >> 3)];
  int j = tid & 7;
  int cnt = deg[node];
  const int* arow = csr + offset[node];
  float a0=0.f,a1=0.f,a2=0.f,a3=0.f,a4=0.f,a5=0.f,a6=0.f,a7=0.f;
  int k = 0;
  for (; k + 8 <= cnt; k += 8) {
    int s[8];
#pragma unroll
    for (int u = 0; u < 8; ++u) s[u] = arow[k + u];
    uint4 v[8];
#pragma unroll
    for (int u = 0; u < 8; ++u) v[u] = *(const uint4*)(xb + (size_t)s[u] * 64 + j * 8);
#pragma unroll
    for (int u = 0; u < 8; ++u) {
      a0 += bf2f(v[u].x & 0xffff); a1 += bf2f(v[u].x >> 16);
      a2 += bf2f(v[u].y & 0xffff); a3 += bf2f(v[u].y >> 16);
      a4 += bf2f(v[u].z & 0xffff); a5 += bf2f(v[u].z >> 16);
      a6 += bf2f(v[u].w & 0xffff); a7 += bf2f(v[u].w >> 16);
    }
  }
  if (k + 4 <= cnt) {
    int s[4];
#pragma unroll
    for (int u = 0; u < 4; ++u) s[u] = arow[k + u];
    uint4 v[4];
#pragma unroll
    for (int u = 0; u < 4; ++u) v[u] = *(const uint4*)(xb + (size_t)s[u] * 64 + j * 8);
#pragma unroll
    for (int u = 0; u < 4; ++u) {
      a0 += bf2f(v[u].x & 0xffff); a1 += bf2f(v[u].x >> 16);
      a2 += bf2f(v[u].y & 0xffff); a3 += bf2f(v[u].y >> 16);
      a4 += bf2f(v[u].z & 0xffff); a5 += bf2f(v[u].z >> 16);
      a6 += bf2f(v[u].w & 0xffff); a7 += bf2f(v[u].w >> 16);
    }
    k += 4;
  }
  for (; k < cnt; ++k) {
    int s = arow[k];
    uint4 v = *(const uint4*)(xb + (size_t)s * 64 + j * 8);
    a0 += bf2f(v.x & 0xffff); a1 += bf2f(v.x >> 16);
    a2 += bf2f(v.y & 0xffff); a3 += bf2f(v.y >> 16);
    a4 += bf2f(v.z & 0xffff); a5 += bf2f(v.z >> 16);
    a6 += bf2f(v.w & 0xffff); a7 += bf2f(v.w >> 16);
  }
  float inv = 1.0f / fmaxf((float)cnt, 1.0f);
  ushort4 r0, r1;
  r0.x = f2bf(a0 * inv); r0.y = f2bf(a1 * inv); r0.z = f2bf(a2 * inv); r0.w = f2bf(a3 * inv);
  r1.x = f2bf(a4 * inv); r1.y = f2bf(a5 * inv); r1.z = f2bf(a6 * inv); r1.w = f2bf(a7 * inv);
  *(ushort4*)(aggB + (size_t)node * 64 + j * 8) = r0;
  *(ushort4*)(aggB + (size_t)node * 64 + j * 8 + 4) = r1;
}

// ---------------- fused MFMA: weight-stationary, async staging, 1 barrier ----------------
__global__ __launch_bounds__(512, 1) void k_gemm12(const unsigned short* __restrict__ aggB,
                                                   const unsigned short* __restrict__ xb,
                                                   const unsigned short* __restrict__ w1c,
                                                   const unsigned short* __restrict__ w2c,
                                                   const float* __restrict__ bn,
                                                   unsigned short* __restrict__ t,
                                                   unsigned short* __restrict__ r2) {
  __shared__ unsigned short w1lds[32 * 512];      // 32KB fragment-major
  __shared__ unsigned short w2lds[32 * 512];      // 32KB fragment-major
  __shared__ unsigned short hlds[8][2][16 * 128]; // 64KB
  __shared__ float bnlds[384];                    // 1.5KB
  const int tid = threadIdx.x;
  const int w = tid >> 6;
  const int lane = tid & 63;
  const int lr = lane & 15;
  const int q = lane >> 4;
  const int tile = blockIdx.x * 8 + w;
  const int base = tile * 32;
  const int nA = base + lr, nB = base + 16 + lr;
  const int cA = min(nA, NN - 1), cB = min(nB, NN - 1);
  const int swz = (lr & 7) << 4;

#pragma unroll
  for (int it = 0; it < 4; ++it) {
    int idx = it * 512 + tid;
    int f = idx >> 6, l = idx & 63;
    int gofs = ((f >> 2) * 16 + (l & 15)) * 128 + (f & 3) * 32 + (l >> 4) * 8;
    gload_lds16(w1c + gofs, &w1lds[(it * 512 + w * 64) * 8]);
    gload_lds16(w2c + gofs, &w2lds[(it * 512 + w * 64) * 8]);
  }
  if (tid < 384) bnlds[tid] = bn[tid];

  bf16x8 fA[4], fB[4];
  {
    const unsigned short* a = aggB + (size_t)cA * 64 + q * 8;
    const unsigned short* xx = xb + (size_t)cA * 64 + q * 8;
    fA[0] = *(const bf16x8*)a;        fA[1] = *(const bf16x8*)(a + 32);
    fA[2] = *(const bf16x8*)xx;       fA[3] = *(const bf16x8*)(xx + 32);
  }
  {
    const unsigned short* a = aggB + (size_t)cB * 64 + q * 8;
    const unsigned short* xx = xb + (size_t)cB * 64 + q * 8;
    fB[0] = *(const bf16x8*)a;        fB[1] = *(const bf16x8*)(a + 32);
    fB[2] = *(const bf16x8*)xx;       fB[3] = *(const bf16x8*)(xx + 32);
  }
  __syncthreads();
  if (base >= NN) return;

  char* ldsA = (char*)&hlds[w][0][0];
  char* ldsB = (char*)&hlds[w][1][0];

#pragma unroll
  for (int ot = 0; ot < 8; ++ot) {
    const unsigned short* wp = &w1lds[(ot * 4) * 512 + lane * 8];
    bf16x8 w0 = *(const bf16x8*)(wp);
    bf16x8 w1 = *(const bf16x8*)(wp + 512);
    bf16x8 w2 = *(const bf16x8*)(wp + 1024);
    bf16x8 w3 = *(const bf16x8*)(wp + 1536);
    f32x4 aA = {0.f, 0.f, 0.f, 0.f}, aB = {0.f, 0.f, 0.f, 0.f};
    aA = __builtin_amdgcn_mfma_f32_16x16x32_bf16(w0, fA[0], aA, 0, 0, 0);
    aA = __builtin_amdgcn_mfma_f32_16x16x32_bf16(w1, fA[1], aA, 0, 0, 0);
    aA = __builtin_amdgcn_mfma_f32_16x16x32_bf16(w2, fA[2], aA, 0, 0, 0);
    aA = __builtin_amdgcn_mfma_f32_16x16x32_bf16(w3, fA[3], aA, 0, 0, 0);
    aB = __builtin_amdgcn_mfma_f32_16x16x32_bf16(w0, fB[0], aB, 0, 0, 0);
    aB = __builtin_amdgcn_mfma_f32_16x16x32_bf16(w1, fB[1], aB, 0, 0, 0);
    aB = __builtin_amdgcn_mfma_f32_16x16x32_bf16(w2, fB[2], aB, 0, 0, 0);
    aB = __builtin_amdgcn_mfma_f32_16x16x32_bf16(w3, fB[3], aB, 0, 0, 0);
    const int o = ot * 16 + q * 4;
    float4 sc = *(const float4*)&bnlds[o];
    float4 sh = *(const float4*)&bnlds[128 + o];
    ushort4 hA, hB;
    hA.x = f2bf(fmaxf(aA[0] * sc.x + sh.x, 0.f));
    hA.y = f2bf(fmaxf(aA[1] * sc.y + sh.y, 0.f));
    hA.z = f2bf(fmaxf(aA[2] * sc.z + sh.z, 0.f));
    hA.w = f2bf(fmaxf(aA[3] * sc.w + sh.w, 0.f));
    hB.x = f2bf(fmaxf(aB[0] * sc.x + sh.x, 0.f));
    hB.y = f2bf(fmaxf(aB[1] * sc.y + sh.y, 0.f));
    hB.z = f2bf(fmaxf(aB[2] * sc.z + sh.z, 0.f));
    hB.w = f2bf(fmaxf(aB[3] * sc.w + sh.w, 0.f));
    const int wb = lr * 256 + ot * 32 + q * 8;
    *(ushort4*)(ldsA + (wb ^ swz)) = hA;
    *(ushort4*)(ldsB + (wb ^ swz)) = hB;
  }

  bf16x8 hA[4], hB[4];
#pragma unroll
  for (int jj = 0; jj < 4; ++jj) {
    const int rb = lr * 256 + jj * 64 + q * 16;
    hA[jj] = *(const bf16x8*)(ldsA + (rb ^ swz));
    hB[jj] = *(const bf16x8*)(ldsB + (rb ^ swz));
  }

#pragma unroll
  for (int ot = 0; ot < 8; ++ot) {
    const unsigned short* wp = &w2lds[(ot * 4) * 512 + lane * 8];
    bf16x8 w0 = *(const bf16x8*)(wp);
    bf16x8 w1 = *(const bf16x8*)(wp + 512);
    bf16x8 w2 = *(const bf16x8*)(wp + 1024);
    bf16x8 w3 = *(const bf16x8*)(wp + 1536);
    f32x4 aA = {0.f, 0.f, 0.f, 0.f}, aB = {0.f, 0.f, 0.f, 0.f};
    aA = __builtin_amdgcn_mfma_f32_16x16x32_bf16(w0, hA[0], aA, 0, 0, 0);
    aA = __builtin_amdgcn_mfma_f32_16x16x32_bf16(w1, hA[1], aA, 0, 0, 0);
    aA = __builtin_amdgcn_mfma_f32_16x16x32_bf16(w2, hA[2], aA, 0, 0, 0);
    aA = __builtin_amdgcn_mfma_f32_16x16x32_bf16(w3, hA[3], aA, 0, 0, 0);
    aB = __builtin_amdgcn_mfma_f32_16x16x32_bf16(w0, hB[0], aB, 0, 0, 0);
    aB = __builtin_amdgcn_mfma_f32_16x16x32_bf16(w1, hB[1], aB, 0, 0, 0);
    aB = __builtin_amdgcn_mfma_f32_16x16x32_bf16(w2, hB[2], aB, 0, 0, 0);
    aB = __builtin_amdgcn_mfma_f32_16x16x32_bf16(w3, hB[3], aB, 0, 0, 0);
    ushort4 tv;
    if (ot < 4) {
      const int o = ot * 16 + q * 4;
      tv.x = f2bf(aA[0]); tv.y = f2bf(aA[1]); tv.z = f2bf(aA[2]); tv.w = f2bf(aA[3]);
      if (nA < NN) *(ushort4*)(t + (size_t)nA * 64 + o) = tv;
      tv.x = f2bf(aB[0]); tv.y = f2bf(aB[1]); tv.z = f2bf(aB[2]); tv.w = f2bf(aB[3]);
      if (nB < NN) *(ushort4*)(t + (size_t)nB * 64 + o) = tv;
    } else {
      const int o = (ot - 4) * 16 + q * 4;
      tv.x = f2bf(aA[0]); tv.y = f2bf(aA[1]); tv.z = f2bf(aA[2]); tv.w = f2bf(aA[3]);
      if (nA < NN) *(ushort4*)(r2 + (size_t)nA * 64 + o) = tv;
      tv.x = f2bf(aB[0]); tv.y = f2bf(aB[1]); tv.z = f2bf(aB[2]); tv.w = f2bf(aB[3]);
      if (nB < NN) *(ushort4*)(r2 + (size_t)nB * 64 + o) = tv;
    }
  }
}

// ---------------- layer2 aggregate + BN2: 8 lanes/node, degree-grouped via perm ----------------
__global__ __launch_bounds__(256) void k_agg2fin(const unsigned short* __restrict__ t,
                                                 const int* __restrict__ deg,
                                                 const int* __restrict__ offset,
                                                 const int* __restrict__ csr,
                                                 const int* __restrict__ perm,
                                                 const unsigned short* __restrict__ r2,
                                                 const float* __restrict__ bn,
                                                 float* __restrict__ outp) {
  int tid = threadIdx.x;
  int node = perm[blockIdx.x * 32 + (tid >> 3)];
  int j = tid & 7;
  int cnt = deg[node];
  const int* arow = csr + offset[node];
  float a0=0.f,a1=0.f,a2=0.f,a3=0.f,a4=0.f,a5=0.f,a6=0.f,a7=0.f;
  int k = 0;
  for (; k + 8 <= cnt; k += 8) {
    int s[8];
#pragma unroll
    for (int u = 0; u < 8; ++u) s[u] = arow[k + u];
    uint4 v[8];
#pragma unroll
    for (int u = 0; u < 8; ++u) v[u] = *(const uint4*)(t + (size_t)s[u] * 64 + j * 8);
#pragma unroll
    for (int u = 0; u < 8; ++u) {
      a0 += bf2f(v[u].x & 0xffff); a1 += bf2f(v[u].x >> 16);
      a2 += bf2f(v[u].y & 0xffff); a3 += bf2f(v[u].y >> 16);
      a4 += bf2f(v[u].z & 0xffff); a5 += bf2f(v[u].z >> 16);
      a6 += bf2f(v[u].w & 0xffff); a7 += bf2f(v[u].w >> 16);
    }
  }
  if (k + 4 <= cnt) {
    int s[4];
#pragma unroll
    for (int u = 0; u < 4; ++u) s[u] = arow[k + u];
    uint4 v[4];
#pragma unroll
    for (int u = 0; u < 4; ++u) v[u] = *(const uint4*)(t + (size_t)s[u] * 64 + j * 8);
#pragma unroll
    for (int u = 0; u < 4; ++u) {
      a0 += bf2f(v[u].x & 0xffff); a1 += bf2f(v[u].x >> 16);
      a2 += bf2f(v[u].y & 0xffff); a3 += bf2f(v[u].y >> 16);
      a4 += bf2f(v[u].z & 0xffff); a5 += bf2f(v[u].z >> 16);
      a6 += bf2f(v[u].w & 0xffff); a7 += bf2f(v[u].w >> 16);
    }
    k += 4;
  }
  for (; k < cnt; ++k) {
    int s = arow[k];
    uint4 v = *(const uint4*)(t + (size_t)s * 64 + j * 8);
    a0 += bf2f(v.x & 0xffff); a1 += bf2f(v.x >> 16);
    a2 += bf2f(v.y & 0xffff); a3 += bf2f(v.y >> 16);
    a4 += bf2f(v.z & 0xffff); a5 += bf2f(v.z >> 16);
    a6 += bf2f(v.w & 0xffff); a7 += bf2f(v.w >> 16);
  }
  float inv = 1.0f / fmaxf((float)cnt, 1.0f);
  int o = j * 8;
  uint4 rv = *(const uint4*)(r2 + (size_t)node * 64 + o);
  float r0 = bf2f(rv.x & 0xffff), r1 = bf2f(rv.x >> 16);
  float r2a = bf2f(rv.y & 0xffff), r3 = bf2f(rv.y >> 16);
  float r4 = bf2f(rv.z & 0xffff), r5 = bf2f(rv.z >> 16);
  float r6 = bf2f(rv.w & 0xffff), r7 = bf2f(rv.w >> 16);
  float4 sca = *(const float4*)(bn + 256 + o);
  float4 scb = *(const float4*)(bn + 256 + o + 4);
  float4 sha = *(const float4*)(bn + 320 + o);
  float4 shb = *(const float4*)(bn + 320 + o + 4);
  float4 o0, o1;
  o0.x = (a0 * inv + r0) * sca.x + sha.x;
  o0.y = (a1 * inv + r1) * sca.y + sha.y;
  o0.z = (a2 * inv + r2a) * sca.z + sha.z;
  o0.w = (a3 * inv + r3) * sca.w + sha.w;
  o1.x = (a4 * inv + r4) * scb.x + shb.x;
  o1.y = (a5 * inv + r5) * scb.y + shb.y;
  o1.z = (a6 * inv + r6) * scb.z + shb.z;
  o1.w = (a7 * inv + r7) * scb.w + shb.w;
  *(float4*)(outp + (size_t)node * 64 + o) = o0;
  *(float4*)(outp + (size_t)node * 64 + o + 4) = o1;
}

extern "C" void kernel_launch(void* const* d_in, const int* in_sizes, int n_in,
                              void* d_out, int out_size, void* d_ws, size_t ws_size,
                              hipStream_t stream) {
  const float* x   = (const float*)d_in[0];
  const int*   ei  = (const int*)d_in[1];
  const float* w1l = (const float*)d_in[2];
  const float* b1l = (const float*)d_in[3];
  const float* w1r = (const float*)d_in[4];
  const float* g1  = (const float*)d_in[5];
  const float* be1 = (const float*)d_in[6];
  const float* m1  = (const float*)d_in[7];
  const float* v1  = (const float*)d_in[8];
  const float* w2l = (const float*)d_in[9];
  const float* b2l = (const float*)d_in[10];
  const float* w2r = (const float*)d_in[11];
  const float* g2  = (const float*)d_in[12];
  const float* be2 = (const float*)d_in[13];
  const float* m2  = (const float*)d_in[14];
  const float* v2  = (const float*)d_in[15];
  float* outp = (float*)d_out;

  char* ws = (char*)d_ws;
  // layout (bytes), 16B-aligned:
  //           0 : tileCnt    (613,120)     [782][196]
  //     613,120 : tileLo     (613,120)     [782][196]
  //   1,226,240 : colBase    (613,120)     [196][782]
  //   1,839,360 : deg        (400,000)     -> 2,239,360
  //   2,239,360 : offset     (400,000)     -> 2,639,360
  //   2,639,360 : pairs      (6,406,144)   -> 9,045,504   (tile-major)
  //   9,045,504 : csr        (6,400,000)   -> 15,445,504
  //  15,445,504 : w1c bf16   (32,768)      -> 15,478,272
  //  15,478,272 : w2c bf16   (32,768)      -> 15,511,040
  //  15,511,040 : bn  fp32   (2,048)       -> 15,513,088
  //  15,513,088 : bdh        (50,176)      -> 15,563,264
  //  15,563,264 : perm       (400,000)     -> 15,963,264
  //  15,963,264 : xb  bf16   (12,800,000)  -> 28,763,264
  //  28,763,264 : aggB bf16  (12,800,000)  -> 41,563,264
  //  41,563,264 : t   bf16   (12,800,000)  -> 54,363,264
  //  54,363,264 : r2  bf16   (12,800,000)  -> 67,163,264  (~67 MB)
  int*            tileCnt = (int*)ws;
  int*            tileLo  = (int*)(ws + 613120);
  int*            colBase = (int*)(ws + 1226240);
  int*            deg     = (int*)(ws + 1839360);
  int*            offset  = (int*)(ws + 2239360);
  unsigned*       pairs   = (unsigned*)(ws + 2639360);
  int*            csr     = (int*)(ws + 9045504);
  unsigned short* w1c     = (unsigned short*)(ws + 15445504);
  unsigned short* w2c     = (unsigned short*)(ws + 15478272);
  float*          bn      = (float*)(ws + 15511040);
  int*            bdh     = (int*)(ws + 15513088);
  int*            perm    = (int*)(ws + 15563264);
  unsigned short* xb      = (unsigned short*)(ws + 15963264);
  unsigned short* aggB    = (unsigned short*)(ws + 28763264);
  unsigned short* t       = (unsigned short*)(ws + 41563264);
  unsigned short* r2      = (unsigned short*)(ws + 54363264);

  const int* srcp = ei;
  const int* dstp = ei + NE;

  hipLaunchKernelGGL(k_binprep, dim3(NTIL + NPREP), dim3(256), 0, stream,
                     srcp, dstp, pairs, tileCnt, tileLo,
                     x, xb, w1l, w1r, w2l, w2r, b1l, g1, be1, m1, v1,
                     b2l, g2, be2, m2, v2, w1c, w2c, bn);
  hipLaunchKernelGGL(k_colscan, dim3(NBUK), dim3(256), 0, stream,
                     tileCnt, colBase);
  hipLaunchKernelGGL(k_build, dim3(NBUK), dim3(512), 0, stream,
                     pairs, tileCnt, tileLo, colBase, deg, offset, csr, bdh);
  hipLaunchKernelGGL(k_perm, dim3(NBUK), dim3(512), 0, stream, bdh, deg, perm);
  hipLaunchKernelGGL(k_aggregate, dim3(NN / 32), dim3(256), 0, stream,
                     xb, deg, offset, csr, perm, aggB);
  hipLaunchKernelGGL(k_gemm12, dim3((NN / 32 + 7) / 8), dim3(512), 0, stream,
                     aggB, xb, w1c, w2c, bn, t, r2);
  hipLaunchKernelGGL(k_agg2fin, dim3(NN / 32), dim3(256), 0, stream,
                     t, deg, offset, csr, perm, r2, bn, outp);
}

// Round 18
// 139.449 us; speedup vs baseline: 1.8331x; 1.8331x over previous
//
#include <hip/hip_runtime.h>

#define NN 100000
#define NE 1600000
#define EPSV 1e-5f

#define NBUK 196       // buckets of 512 nodes: bucket = dst >> 9
#define TILE 2048      // edges per k_bin tile
#define NTIL 782       // ceil(NE / TILE); last tile has 512 edges
#define NPREP 6250     // x-conversion blocks (6250*1024 floats = 6.4M)
#define CAP  9216      // per-bucket capacity (mean 8163, sigma ~90 -> +11 sigma)

typedef __attribute__((ext_vector_type(8))) short bf16x8;
typedef __attribute__((ext_vector_type(4))) float f32x4;

__device__ inline unsigned short f2bf(float f) {
  unsigned u = __builtin_bit_cast(unsigned, f);
  unsigned r = u + 0x7FFFu + ((u >> 16) & 1u);
  return (unsigned short)(r >> 16);
}
__device__ inline float bf2f(unsigned short s) {
  unsigned u = ((unsigned)s) << 16;
  return __builtin_bit_cast(float, u);
}

// async global->LDS, 16B per lane; LDS dest = wave-uniform base + lane*16
__device__ __forceinline__ void gload_lds16(const unsigned short* g, unsigned short* l) {
  __builtin_amdgcn_global_load_lds(
      (const __attribute__((address_space(1))) void*)g,
      (__attribute__((address_space(3))) void*)l, 16, 0, 0);
}

// ---------------- phase 1 (merged): blocks<NTIL = tile bucket-sort; rest = prep ----------------
__global__ __launch_bounds__(256) void k_binprep(const int* __restrict__ src,
                                                 const int* __restrict__ dst,
                                                 unsigned* __restrict__ pairs,
                                                 int* __restrict__ tileCnt,
                                                 int* __restrict__ tileLo,
                                                 const float* __restrict__ x,
                                                 unsigned short* __restrict__ xb,
                                                 const float* __restrict__ w1l,
                                                 const float* __restrict__ w1r,
                                                 const float* __restrict__ w2l,
                                                 const float* __restrict__ w2r,
                                                 const float* __restrict__ b1l,
                                                 const float* __restrict__ g1,
                                                 const float* __restrict__ be1,
                                                 const float* __restrict__ m1,
                                                 const float* __restrict__ v1,
                                                 const float* __restrict__ b2l,
                                                 const float* __restrict__ g2,
                                                 const float* __restrict__ be2,
                                                 const float* __restrict__ m2,
                                                 const float* __restrict__ v2,
                                                 unsigned short* __restrict__ w1c,
                                                 unsigned short* __restrict__ w2c,
                                                 float* __restrict__ bn) {
  const int tid = threadIdx.x;
  if (blockIdx.x >= NTIL) {
    const int pb = blockIdx.x - NTIL;
    const int gi = pb * 256 + tid;
    float4 v = *(const float4*)(x + (size_t)gi * 4);
    ushort4 o;
    o.x = f2bf(v.x); o.y = f2bf(v.y); o.z = f2bf(v.z); o.w = f2bf(v.w);
    *(ushort4*)(xb + (size_t)gi * 4) = o;
    if (pb < 64) {
      int i = pb * 256 + tid;  // 0..16383
      int oo = i >> 7, k = i & 127;
      float vv1 = (k < 64) ? w1l[oo * 64 + k] : w1r[oo * 64 + (k - 64)];
      w1c[i] = f2bf(vv1);
      float vv2 = (oo < 64) ? w2l[oo * 128 + k] : w2r[(oo - 64) * 128 + k];
      w2c[i] = f2bf(vv2);
      if (i < 128) {
        float sc = g1[i] * rsqrtf(v1[i] + EPSV);
        bn[i] = sc;
        bn[128 + i] = (b1l[i] - m1[i]) * sc + be1[i];
      }
      if (i < 64) {
        float sc = g2[i] * rsqrtf(v2[i] + EPSV);
        bn[256 + i] = sc;
        bn[320 + i] = (b2l[i] - m2[i]) * sc + be2[i];
      }
    }
    return;
  }
  __shared__ int cnt[NBUK];
  __shared__ int lo[NBUK];
  __shared__ int ts[256];
  __shared__ unsigned stage[TILE];
  const int t = blockIdx.x;
  const int e0 = t * TILE;
  const int m = min(TILE, NE - e0);

  int dreg[8], sreg[8];
#pragma unroll
  for (int u = 0; u < 8; ++u) {
    int i = u * 256 + tid;
    if (i < m) {
      dreg[u] = dst[e0 + i];
      sreg[u] = src[e0 + i];
    } else {
      dreg[u] = -1;
    }
  }

  for (int i = tid; i < NBUK; i += 256) cnt[i] = 0;
  __syncthreads();
#pragma unroll
  for (int u = 0; u < 8; ++u) {
    if (dreg[u] >= 0) atomicAdd(&cnt[dreg[u] >> 9], 1);
  }
  __syncthreads();
  int c = (tid < NBUK) ? cnt[tid] : 0;
  ts[tid] = c;
  __syncthreads();
  for (int d = 1; d < 256; d <<= 1) {
    int v = (tid >= d) ? ts[tid - d] : 0;
    __syncthreads();
    ts[tid] += v;
    __syncthreads();
  }
  if (tid < NBUK) {
    int ex = ts[tid] - c;
    lo[tid] = ex;
    cnt[tid] = ex;
  }
  __syncthreads();
#pragma unroll
  for (int u = 0; u < 8; ++u) {
    if (dreg[u] >= 0) {
      int pos = atomicAdd(&cnt[dreg[u] >> 9], 1);
      stage[pos] = ((unsigned)(dreg[u] & 511) << 17) | (unsigned)sreg[u];
    }
  }
  __syncthreads();
  for (int i = tid; i < m; i += 256) pairs[(size_t)t * TILE + i] = stage[i];
  if (tid < NBUK) {
    tileCnt[t * NBUK + tid] = cnt[tid] - lo[tid];
    tileLo[t * NBUK + tid] = lo[tid];
  }
}

// ---------------- phase 1.5: per-bucket prefix over tiles ----------------
__global__ __launch_bounds__(256) void k_colscan(const int* __restrict__ tileCnt,
                                                 int* __restrict__ colBase) {
  __shared__ int ts[256];
  const int tid = threadIdx.x;
  const int b = blockIdx.x;
  int v[4];
  int s = 0;
#pragma unroll
  for (int j = 0; j < 4; ++j) {
    int tt = tid * 4 + j;
    v[j] = (tt < NTIL) ? tileCnt[tt * NBUK + b] : 0;
    s += v[j];
  }
  ts[tid] = s;
  __syncthreads();
  for (int d = 1; d < 256; d <<= 1) {
    int x = (tid >= d) ? ts[tid - d] : 0;
    __syncthreads();
    ts[tid] += x;
    __syncthreads();
  }
  int run = ts[tid] - s;
#pragma unroll
  for (int j = 0; j < 4; ++j) {
    int tt = tid * 4 + j;
    if (tt < NTIL) colBase[(size_t)b * NTIL + tt] = run;
    run += v[j];
  }
}

// ---------------- phase 2: per-bucket CSR build via GATHER + degree histogram ----------------
__global__ __launch_bounds__(512) void k_build(const unsigned* __restrict__ pairs,
                                               const int* __restrict__ tileCnt,
                                               const int* __restrict__ tileLo,
                                               const int* __restrict__ colBase,
                                               int* __restrict__ deg,
                                               int* __restrict__ offset,
                                               int* __restrict__ csr,
                                               int* __restrict__ bdh) {
  __shared__ unsigned stageA[CAP];
  __shared__ unsigned stageB[CAP];
  __shared__ int colB[NTIL];
  __shared__ int tLo[NTIL];
  __shared__ int hist[512];
  __shared__ int ts[512];
  __shared__ int dh[64];
  __shared__ int obase_sh, count_sh;
  const int tid = threadIdx.x;
  const int b = blockIdx.x;
  const int nbase = b * 512;
  const int nloc = min(512, NN - nbase);

  int tb = 0;
  if (tid < NBUK) {
    int cb = colBase[(size_t)tid * NTIL + (NTIL - 1)];
    int tc = tileCnt[(NTIL - 1) * NBUK + tid];
    tb = min(cb + tc, CAP);
  }
  ts[tid] = tb;
  if (tid < 64) dh[tid] = 0;
  __syncthreads();
  for (int d = 1; d < 512; d <<= 1) {
    int v = (tid >= d) ? ts[tid - d] : 0;
    __syncthreads();
    ts[tid] += v;
    __syncthreads();
  }
  if (tid == b) { obase_sh = ts[tid] - tb; count_sh = tb; }
  for (int i = tid; i < NTIL; i += 512) {
    colB[i] = colBase[(size_t)b * NTIL + i];
    tLo[i] = tileLo[i * NBUK + b];
  }
  hist[tid] = 0;
  __syncthreads();
  const int obase = obase_sh;
  const int count = count_sh;

  for (int i = tid; i < count; i += 512) {
    int a = 0, z = NTIL - 1;
    while (a < z) {
      int mid = (a + z + 1) >> 1;
      if (colB[mid] <= i) a = mid; else z = mid - 1;
    }
    stageA[i] = pairs[(size_t)a * TILE + tLo[a] + (i - colB[a])];
  }
  __syncthreads();
  for (int i = tid; i < count; i += 512) {
    atomicAdd(&hist[stageA[i] >> 17], 1);
  }
  __syncthreads();
  int s = hist[tid];
  ts[tid] = s;
  __syncthreads();
  for (int d = 1; d < 512; d <<= 1) {
    int v = (tid >= d) ? ts[tid - d] : 0;
    __syncthreads();
    ts[tid] += v;
    __syncthreads();
  }
  int ex = ts[tid] - s;
  if (tid < nloc) {
    deg[nbase + tid] = s;
    offset[nbase + tid] = obase + ex;
    atomicAdd(&dh[min(s, 63)], 1);
  }
  hist[tid] = ex;
  __syncthreads();
  if (tid < 64) bdh[b * 64 + tid] = dh[tid];
  for (int i = tid; i < count; i += 512) {
    unsigned e = stageA[i];
    int pos = atomicAdd(&hist[e >> 17], 1);
    stageB[pos] = e & 0x1FFFFu;
  }
  __syncthreads();
  for (int i = tid; i < count; i += 512) csr[obase + i] = (int)stageB[i];
}

// ---------------- phase 2.5a: bin bases + per-(bucket,bin) cursor init (ONE block) ----------------
__global__ __launch_bounds__(512) void k_permA(const int* __restrict__ bdh,
                                               int* __restrict__ curInit) {
  __shared__ int h[NBUK * 64];   // 50,176 B
  __shared__ int binTot[64];
  __shared__ int binBase[64];
  const int tid = threadIdx.x;
  for (int i = tid; i < NBUK * 64; i += 512) h[i] = bdh[i];
  __syncthreads();
  if (tid < 64) {
    int s = 0;
    for (int bb = 0; bb < NBUK; ++bb) s += h[bb * 64 + tid];
    binTot[tid] = s;
  }
  __syncthreads();
  if (tid == 0) {
    int run = 0;
    for (int d = 0; d < 64; ++d) { binBase[d] = run; run += binTot[d]; }
  }
  __syncthreads();
  if (tid < 64) {
    int run = binBase[tid];
    for (int bb = 0; bb < NBUK; ++bb) {
      curInit[bb * 64 + tid] = run;   // threads 0..63 write 256B coalesced per bb
      run += h[bb * 64 + tid];
    }
  }
}

// ---------------- phase 2.5b: place nodes into degree-grouped perm ----------------
__global__ __launch_bounds__(512) void k_permB(const int* __restrict__ curInit,
                                               const int* __restrict__ deg,
                                               int* __restrict__ perm) {
  __shared__ int cur[64];
  const int tid = threadIdx.x;
  const int b = blockIdx.x;
  if (tid < 64) cur[tid] = curInit[b * 64 + tid];
  __syncthreads();
  const int node = b * 512 + tid;
  if (node < NN) {
    int bin = min(deg[node], 63);
    int pos = atomicAdd(&cur[bin], 1);
    perm[pos] = node;
  }
}

// ---------------- mean-aggregate: 8 lanes/node, degree-grouped via perm ----------------
__global__ __launch_bounds__(256) void k_aggregate(const unsigned short* __restrict__ xb,
                                                   const int* __restrict__ deg,
                                                   const int* __restrict__ offset,
                                                   const int* __restrict__ csr,
                                                   const int* __restrict__ perm,
                                                   unsigned short* __restrict__ aggB) {
  int tid = threadIdx.x;
  int node = perm[blockIdx.x * 32 + (tid >> 3)];
  int j = tid & 7;
  int cnt = deg[node];
  const int* arow = csr + offset[node];
  float a0=0.f,a1=0.f,a2=0.f,a3=0.f,a4=0.f,a5=0.f,a6=0.f,a7=0.f;
  int k = 0;
  for (; k + 8 <= cnt; k += 8) {
    int s[8];
#pragma unroll
    for (int u = 0; u < 8; ++u) s[u] = arow[k + u];
    uint4 v[8];
#pragma unroll
    for (int u = 0; u < 8; ++u) v[u] = *(const uint4*)(xb + (size_t)s[u] * 64 + j * 8);
#pragma unroll
    for (int u = 0; u < 8; ++u) {
      a0 += bf2f(v[u].x & 0xffff); a1 += bf2f(v[u].x >> 16);
      a2 += bf2f(v[u].y & 0xffff); a3 += bf2f(v[u].y >> 16);
      a4 += bf2f(v[u].z & 0xffff); a5 += bf2f(v[u].z >> 16);
      a6 += bf2f(v[u].w & 0xffff); a7 += bf2f(v[u].w >> 16);
    }
  }
  if (k + 4 <= cnt) {
    int s[4];
#pragma unroll
    for (int u = 0; u < 4; ++u) s[u] = arow[k + u];
    uint4 v[4];
#pragma unroll
    for (int u = 0; u < 4; ++u) v[u] = *(const uint4*)(xb + (size_t)s[u] * 64 + j * 8);
#pragma unroll
    for (int u = 0; u < 4; ++u) {
      a0 += bf2f(v[u].x & 0xffff); a1 += bf2f(v[u].x >> 16);
      a2 += bf2f(v[u].y & 0xffff); a3 += bf2f(v[u].y >> 16);
      a4 += bf2f(v[u].z & 0xffff); a5 += bf2f(v[u].z >> 16);
      a6 += bf2f(v[u].w & 0xffff); a7 += bf2f(v[u].w >> 16);
    }
    k += 4;
  }
  for (; k < cnt; ++k) {
    int s = arow[k];
    uint4 v = *(const uint4*)(xb + (size_t)s * 64 + j * 8);
    a0 += bf2f(v.x & 0xffff); a1 += bf2f(v.x >> 16);
    a2 += bf2f(v.y & 0xffff); a3 += bf2f(v.y >> 16);
    a4 += bf2f(v.z & 0xffff); a5 += bf2f(v.z >> 16);
    a6 += bf2f(v.w & 0xffff); a7 += bf2f(v.w >> 16);
  }
  float inv = 1.0f / fmaxf((float)cnt, 1.0f);
  ushort4 r0, r1;
  r0.x = f2bf(a0 * inv); r0.y = f2bf(a1 * inv); r0.z = f2bf(a2 * inv); r0.w = f2bf(a3 * inv);
  r1.x = f2bf(a4 * inv); r1.y = f2bf(a5 * inv); r1.z = f2bf(a6 * inv); r1.w = f2bf(a7 * inv);
  *(ushort4*)(aggB + (size_t)node * 64 + j * 8) = r0;
  *(ushort4*)(aggB + (size_t)node * 64 + j * 8 + 4) = r1;
}

// ---------------- fused MFMA: weight-stationary, async staging, 1 barrier ----------------
__global__ __launch_bounds__(512, 1) void k_gemm12(const unsigned short* __restrict__ aggB,
                                                   const unsigned short* __restrict__ xb,
                                                   const unsigned short* __restrict__ w1c,
                                                   const unsigned short* __restrict__ w2c,
                                                   const float* __restrict__ bn,
                                                   unsigned short* __restrict__ t,
                                                   unsigned short* __restrict__ r2) {
  __shared__ unsigned short w1lds[32 * 512];      // 32KB fragment-major
  __shared__ unsigned short w2lds[32 * 512];      // 32KB fragment-major
  __shared__ unsigned short hlds[8][2][16 * 128]; // 64KB
  __shared__ float bnlds[384];                    // 1.5KB
  const int tid = threadIdx.x;
  const int w = tid >> 6;
  const int lane = tid & 63;
  const int lr = lane & 15;
  const int q = lane >> 4;
  const int tile = blockIdx.x * 8 + w;
  const int base = tile * 32;
  const int nA = base + lr, nB = base + 16 + lr;
  const int cA = min(nA, NN - 1), cB = min(nB, NN - 1);
  const int swz = (lr & 7) << 4;

#pragma unroll
  for (int it = 0; it < 4; ++it) {
    int idx = it * 512 + tid;
    int f = idx >> 6, l = idx & 63;
    int gofs = ((f >> 2) * 16 + (l & 15)) * 128 + (f & 3) * 32 + (l >> 4) * 8;
    gload_lds16(w1c + gofs, &w1lds[(it * 512 + w * 64) * 8]);
    gload_lds16(w2c + gofs, &w2lds[(it * 512 + w * 64) * 8]);
  }
  if (tid < 384) bnlds[tid] = bn[tid];

  bf16x8 fA[4], fB[4];
  {
    const unsigned short* a = aggB + (size_t)cA * 64 + q * 8;
    const unsigned short* xx = xb + (size_t)cA * 64 + q * 8;
    fA[0] = *(const bf16x8*)a;        fA[1] = *(const bf16x8*)(a + 32);
    fA[2] = *(const bf16x8*)xx;       fA[3] = *(const bf16x8*)(xx + 32);
  }
  {
    const unsigned short* a = aggB + (size_t)cB * 64 + q * 8;
    const unsigned short* xx = xb + (size_t)cB * 64 + q * 8;
    fB[0] = *(const bf16x8*)a;        fB[1] = *(const bf16x8*)(a + 32);
    fB[2] = *(const bf16x8*)xx;       fB[3] = *(const bf16x8*)(xx + 32);
  }
  __syncthreads();
  if (base >= NN) return;

  char* ldsA = (char*)&hlds[w][0][0];
  char* ldsB = (char*)&hlds[w][1][0];

#pragma unroll
  for (int ot = 0; ot < 8; ++ot) {
    const unsigned short* wp = &w1lds[(ot * 4) * 512 + lane * 8];
    bf16x8 w0 = *(const bf16x8*)(wp);
    bf16x8 w1 = *(const bf16x8*)(wp + 512);
    bf16x8 w2 = *(const bf16x8*)(wp + 1024);
    bf16x8 w3 = *(const bf16x8*)(wp + 1536);
    f32x4 aA = {0.f, 0.f, 0.f, 0.f}, aB = {0.f, 0.f, 0.f, 0.f};
    aA = __builtin_amdgcn_mfma_f32_16x16x32_bf16(w0, fA[0], aA, 0, 0, 0);
    aA = __builtin_amdgcn_mfma_f32_16x16x32_bf16(w1, fA[1], aA, 0, 0, 0);
    aA = __builtin_amdgcn_mfma_f32_16x16x32_bf16(w2, fA[2], aA, 0, 0, 0);
    aA = __builtin_amdgcn_mfma_f32_16x16x32_bf16(w3, fA[3], aA, 0, 0, 0);
    aB = __builtin_amdgcn_mfma_f32_16x16x32_bf16(w0, fB[0], aB, 0, 0, 0);
    aB = __builtin_amdgcn_mfma_f32_16x16x32_bf16(w1, fB[1], aB, 0, 0, 0);
    aB = __builtin_amdgcn_mfma_f32_16x16x32_bf16(w2, fB[2], aB, 0, 0, 0);
    aB = __builtin_amdgcn_mfma_f32_16x16x32_bf16(w3, fB[3], aB, 0, 0, 0);
    const int o = ot * 16 + q * 4;
    float4 sc = *(const float4*)&bnlds[o];
    float4 sh = *(const float4*)&bnlds[128 + o];
    ushort4 hA, hB;
    hA.x = f2bf(fmaxf(aA[0] * sc.x + sh.x, 0.f));
    hA.y = f2bf(fmaxf(aA[1] * sc.y + sh.y, 0.f));
    hA.z = f2bf(fmaxf(aA[2] * sc.z + sh.z, 0.f));
    hA.w = f2bf(fmaxf(aA[3] * sc.w + sh.w, 0.f));
    hB.x = f2bf(fmaxf(aB[0] * sc.x + sh.x, 0.f));
    hB.y = f2bf(fmaxf(aB[1] * sc.y + sh.y, 0.f));
    hB.z = f2bf(fmaxf(aB[2] * sc.z + sh.z, 0.f));
    hB.w = f2bf(fmaxf(aB[3] * sc.w + sh.w, 0.f));
    const int wb = lr * 256 + ot * 32 + q * 8;
    *(ushort4*)(ldsA + (wb ^ swz)) = hA;
    *(ushort4*)(ldsB + (wb ^ swz)) = hB;
  }

  bf16x8 hA[4], hB[4];
#pragma unroll
  for (int jj = 0; jj < 4; ++jj) {
    const int rb = lr * 256 + jj * 64 + q * 16;
    hA[jj] = *(const bf16x8*)(ldsA + (rb ^ swz));
    hB[jj] = *(const bf16x8*)(ldsB + (rb ^ swz));
  }

#pragma unroll
  for (int ot = 0; ot < 8; ++ot) {
    const unsigned short* wp = &w2lds[(ot * 4) * 512 + lane * 8];
    bf16x8 w0 = *(const bf16x8*)(wp);
    bf16x8 w1 = *(const bf16x8*)(wp + 512);
    bf16x8 w2 = *(const bf16x8*)(wp + 1024);
    bf16x8 w3 = *(const bf16x8*)(wp + 1536);
    f32x4 aA = {0.f, 0.f, 0.f, 0.f}, aB = {0.f, 0.f, 0.f, 0.f};
    aA = __builtin_amdgcn_mfma_f32_16x16x32_bf16(w0, hA[0], aA, 0, 0, 0);
    aA = __builtin_amdgcn_mfma_f32_16x16x32_bf16(w1, hA[1], aA, 0, 0, 0);
    aA = __builtin_amdgcn_mfma_f32_16x16x32_bf16(w2, hA[2], aA, 0, 0, 0);
    aA = __builtin_amdgcn_mfma_f32_16x16x32_bf16(w3, hA[3], aA, 0, 0, 0);
    aB = __builtin_amdgcn_mfma_f32_16x16x32_bf16(w0, hB[0], aB, 0, 0, 0);
    aB = __builtin_amdgcn_mfma_f32_16x16x32_bf16(w1, hB[1], aB, 0, 0, 0);
    aB = __builtin_amdgcn_mfma_f32_16x16x32_bf16(w2, hB[2], aB, 0, 0, 0);
    aB = __builtin_amdgcn_mfma_f32_16x16x32_bf16(w3, hB[3], aB, 0, 0, 0);
    ushort4 tv;
    if (ot < 4) {
      const int o = ot * 16 + q * 4;
      tv.x = f2bf(aA[0]); tv.y = f2bf(aA[1]); tv.z = f2bf(aA[2]); tv.w = f2bf(aA[3]);
      if (nA < NN) *(ushort4*)(t + (size_t)nA * 64 + o) = tv;
      tv.x = f2bf(aB[0]); tv.y = f2bf(aB[1]); tv.z = f2bf(aB[2]); tv.w = f2bf(aB[3]);
      if (nB < NN) *(ushort4*)(t + (size_t)nB * 64 + o) = tv;
    } else {
      const int o = (ot - 4) * 16 + q * 4;
      tv.x = f2bf(aA[0]); tv.y = f2bf(aA[1]); tv.z = f2bf(aA[2]); tv.w = f2bf(aA[3]);
      if (nA < NN) *(ushort4*)(r2 + (size_t)nA * 64 + o) = tv;
      tv.x = f2bf(aB[0]); tv.y = f2bf(aB[1]); tv.z = f2bf(aB[2]); tv.w = f2bf(aB[3]);
      if (nB < NN) *(ushort4*)(r2 + (size_t)nB * 64 + o) = tv;
    }
  }
}

// ---------------- layer2 aggregate + BN2: 8 lanes/node, degree-grouped via perm ----------------
__global__ __launch_bounds__(256) void k_agg2fin(const unsigned short* __restrict__ t,
                                                 const int* __restrict__ deg,
                                                 const int* __restrict__ offset,
                                                 const int* __restrict__ csr,
                                                 const int* __restrict__ perm,
                                                 const unsigned short* __restrict__ r2,
                                                 const float* __restrict__ bn,
                                                 float* __restrict__ outp) {
  int tid = threadIdx.x;
  int node = perm[blockIdx.x * 32 + (tid >> 3)];
  int j = tid & 7;
  int cnt = deg[node];
  const int* arow = csr + offset[node];
  float a0=0.f,a1=0.f,a2=0.f,a3=0.f,a4=0.f,a5=0.f,a6=0.f,a7=0.f;
  int k = 0;
  for (; k + 8 <= cnt; k += 8) {
    int s[8];
#pragma unroll
    for (int u = 0; u < 8; ++u) s[u] = arow[k + u];
    uint4 v[8];
#pragma unroll
    for (int u = 0; u < 8; ++u) v[u] = *(const uint4*)(t + (size_t)s[u] * 64 + j * 8);
#pragma unroll
    for (int u = 0; u < 8; ++u) {
      a0 += bf2f(v[u].x & 0xffff); a1 += bf2f(v[u].x >> 16);
      a2 += bf2f(v[u].y & 0xffff); a3 += bf2f(v[u].y >> 16);
      a4 += bf2f(v[u].z & 0xffff); a5 += bf2f(v[u].z >> 16);
      a6 += bf2f(v[u].w & 0xffff); a7 += bf2f(v[u].w >> 16);
    }
  }
  if (k + 4 <= cnt) {
    int s[4];
#pragma unroll
    for (int u = 0; u < 4; ++u) s[u] = arow[k + u];
    uint4 v[4];
#pragma unroll
    for (int u = 0; u < 4; ++u) v[u] = *(const uint4*)(t + (size_t)s[u] * 64 + j * 8);
#pragma unroll
    for (int u = 0; u < 4; ++u) {
      a0 += bf2f(v[u].x & 0xffff); a1 += bf2f(v[u].x >> 16);
      a2 += bf2f(v[u].y & 0xffff); a3 += bf2f(v[u].y >> 16);
      a4 += bf2f(v[u].z & 0xffff); a5 += bf2f(v[u].z >> 16);
      a6 += bf2f(v[u].w & 0xffff); a7 += bf2f(v[u].w >> 16);
    }
    k += 4;
  }
  for (; k < cnt; ++k) {
    int s = arow[k];
    uint4 v = *(const uint4*)(t + (size_t)s * 64 + j * 8);
    a0 += bf2f(v.x & 0xffff); a1 += bf2f(v.x >> 16);
    a2 += bf2f(v.y & 0xffff); a3 += bf2f(v.y >> 16);
    a4 += bf2f(v.z & 0xffff); a5 += bf2f(v.z >> 16);
    a6 += bf2f(v.w & 0xffff); a7 += bf2f(v.w >> 16);
  }
  float inv = 1.0f / fmaxf((float)cnt, 1.0f);
  int o = j * 8;
  uint4 rv = *(const uint4*)(r2 + (size_t)node * 64 + o);
  float r0 = bf2f(rv.x & 0xffff), r1 = bf2f(rv.x >> 16);
  float r2a = bf2f(rv.y & 0xffff), r3 = bf2f(rv.y >> 16);
  float r4 = bf2f(rv.z & 0xffff), r5 = bf2f(rv.z >> 16);
  float r6 = bf2f(rv.w & 0xffff), r7 = bf2f(rv.w >> 16);
  float4 sca = *(const float4*)(bn + 256 + o);
  float4 scb = *(const float4*)(bn + 256 + o + 4);
  float4 sha = *(const float4*)(bn + 320 + o);
  float4 shb = *(const float4*)(bn + 320 + o + 4);
  float4 o0, o1;
  o0.x = (a0 * inv + r0) * sca.x + sha.x;
  o0.y = (a1 * inv + r1) * sca.y + sha.y;
  o0.z = (a2 * inv + r2a) * sca.z + sha.z;
  o0.w = (a3 * inv + r3) * sca.w + sha.w;
  o1.x = (a4 * inv + r4) * scb.x + shb.x;
  o1.y = (a5 * inv + r5) * scb.y + shb.y;
  o1.z = (a6 * inv + r6) * scb.z + shb.z;
  o1.w = (a7 * inv + r7) * scb.w + shb.w;
  *(float4*)(outp + (size_t)node * 64 + o) = o0;
  *(float4*)(outp + (size_t)node * 64 + o + 4) = o1;
}

extern "C" void kernel_launch(void* const* d_in, const int* in_sizes, int n_in,
                              void* d_out, int out_size, void* d_ws, size_t ws_size,
                              hipStream_t stream) {
  const float* x   = (const float*)d_in[0];
  const int*   ei  = (const int*)d_in[1];
  const float* w1l = (const float*)d_in[2];
  const float* b1l = (const float*)d_in[3];
  const float* w1r = (const float*)d_in[4];
  const float* g1  = (const float*)d_in[5];
  const float* be1 = (const float*)d_in[6];
  const float* m1  = (const float*)d_in[7];
  const float* v1  = (const float*)d_in[8];
  const float* w2l = (const float*)d_in[9];
  const float* b2l = (const float*)d_in[10];
  const float* w2r = (const float*)d_in[11];
  const float* g2  = (const float*)d_in[12];
  const float* be2 = (const float*)d_in[13];
  const float* m2  = (const float*)d_in[14];
  const float* v2  = (const float*)d_in[15];
  float* outp = (float*)d_out;

  char* ws = (char*)d_ws;
  // layout (bytes), 16B-aligned:
  //           0 : tileCnt    (613,120)     [782][196]
  //     613,120 : tileLo     (613,120)     [782][196]
  //   1,226,240 : colBase    (613,120)     [196][782]
  //   1,839,360 : deg        (400,000)     -> 2,239,360
  //   2,239,360 : offset     (400,000)     -> 2,639,360
  //   2,639,360 : pairs      (6,406,144)   -> 9,045,504   (tile-major)
  //   9,045,504 : csr        (6,400,000)   -> 15,445,504
  //  15,445,504 : w1c bf16   (32,768)      -> 15,478,272
  //  15,478,272 : w2c bf16   (32,768)      -> 15,511,040
  //  15,511,040 : bn  fp32   (2,048)       -> 15,513,088
  //  15,513,088 : bdh        (50,176)      -> 15,563,264
  //  15,563,264 : curInit    (50,176)      -> 15,613,440
  //  15,613,440 : perm       (400,000)     -> 16,013,440
  //  16,013,440 : xb  bf16   (12,800,000)  -> 28,813,440
  //  28,813,440 : aggB bf16  (12,800,000)  -> 41,613,440
  //  41,613,440 : t   bf16   (12,800,000)  -> 54,413,440
  //  54,413,440 : r2  bf16   (12,800,000)  -> 67,213,440  (~67 MB)
  int*            tileCnt = (int*)ws;
  int*            tileLo  = (int*)(ws + 613120);
  int*            colBase = (int*)(ws + 1226240);
  int*            deg     = (int*)(ws + 1839360);
  int*            offset  = (int*)(ws + 2239360);
  unsigned*       pairs   = (unsigned*)(ws + 2639360);
  int*            csr     = (int*)(ws + 9045504);
  unsigned short* w1c     = (unsigned short*)(ws + 15445504);
  unsigned short* w2c     = (unsigned short*)(ws + 15478272);
  float*          bn      = (float*)(ws + 15511040);
  int*            bdh     = (int*)(ws + 15513088);
  int*            curInit = (int*)(ws + 15563264);
  int*            perm    = (int*)(ws + 15613440);
  unsigned short* xb      = (unsigned short*)(ws + 16013440);
  unsigned short* aggB    = (unsigned short*)(ws + 28813440);
  unsigned short* t       = (unsigned short*)(ws + 41613440);
  unsigned short* r2      = (unsigned short*)(ws + 54413440);

  const int* srcp = ei;
  const int* dstp = ei + NE;

  hipLaunchKernelGGL(k_binprep, dim3(NTIL + NPREP), dim3(256), 0, stream,
                     srcp, dstp, pairs, tileCnt, tileLo,
                     x, xb, w1l, w1r, w2l, w2r, b1l, g1, be1, m1, v1,
                     b2l, g2, be2, m2, v2, w1c, w2c, bn);
  hipLaunchKernelGGL(k_colscan, dim3(NBUK), dim3(256), 0, stream,
                     tileCnt, colBase);
  hipLaunchKernelGGL(k_build, dim3(NBUK), dim3(512), 0, stream,
                     pairs, tileCnt, tileLo, colBase, deg, offset, csr, bdh);
  hipLaunchKernelGGL(k_permA, dim3(1), dim3(512), 0, stream, bdh, curInit);
  hipLaunchKernelGGL(k_permB, dim3(NBUK), dim3(512), 0, stream,
                     curInit, deg, perm);
  hipLaunchKernelGGL(k_aggregate, dim3(NN / 32), dim3(256), 0, stream,
                     xb, deg, offset, csr, perm, aggB);
  hipLaunchKernelGGL(k_gemm12, dim3((NN / 32 + 7) / 8), dim3(512), 0, stream,
                     aggB, xb, w1c, w2c, bn, t, r2);
  hipLaunchKernelGGL(k_agg2fin, dim3(NN / 32), dim3(256), 0, stream,
                     t, deg, offset, csr, perm, r2, bn, outp);
}

// Round 19
// 128.904 us; speedup vs baseline: 1.9831x; 1.0818x over previous
//
#include <hip/hip_runtime.h>

#define NN 100000
#define NE 1600000
#define EPSV 1e-5f

#define NBUK 196       // buckets of 512 nodes: bucket = dst >> 9
#define TILE 2048      // edges per k_bin tile
#define NTIL 782       // ceil(NE / TILE); last tile has 512 edges
#define NPREP 6250     // x-conversion blocks (6250*1024 floats = 6.4M)
#define CAP  9216      // per-bucket capacity (mean 8163, sigma ~90 -> +11 sigma)

typedef __attribute__((ext_vector_type(8))) short bf16x8;
typedef __attribute__((ext_vector_type(4))) float f32x4;

__device__ inline unsigned short f2bf(float f) {
  unsigned u = __builtin_bit_cast(unsigned, f);
  unsigned r = u + 0x7FFFu + ((u >> 16) & 1u);
  return (unsigned short)(r >> 16);
}
__device__ inline float bf2f(unsigned short s) {
  unsigned u = ((unsigned)s) << 16;
  return __builtin_bit_cast(float, u);
}

// async global->LDS, 16B per lane; LDS dest = wave-uniform base + lane*16
__device__ __forceinline__ void gload_lds16(const unsigned short* g, unsigned short* l) {
  __builtin_amdgcn_global_load_lds(
      (const __attribute__((address_space(1))) void*)g,
      (__attribute__((address_space(3))) void*)l, 16, 0, 0);
}

// ---------------- phase 1 (merged): blocks<NTIL = tile bucket-sort; rest = prep ----------------
__global__ __launch_bounds__(256) void k_binprep(const int* __restrict__ src,
                                                 const int* __restrict__ dst,
                                                 unsigned* __restrict__ pairs,
                                                 int* __restrict__ tileCnt,
                                                 int* __restrict__ tileLo,
                                                 const float* __restrict__ x,
                                                 unsigned short* __restrict__ xb,
                                                 const float* __restrict__ w1l,
                                                 const float* __restrict__ w1r,
                                                 const float* __restrict__ w2l,
                                                 const float* __restrict__ w2r,
                                                 const float* __restrict__ b1l,
                                                 const float* __restrict__ g1,
                                                 const float* __restrict__ be1,
                                                 const float* __restrict__ m1,
                                                 const float* __restrict__ v1,
                                                 const float* __restrict__ b2l,
                                                 const float* __restrict__ g2,
                                                 const float* __restrict__ be2,
                                                 const float* __restrict__ m2,
                                                 const float* __restrict__ v2,
                                                 unsigned short* __restrict__ w1c,
                                                 unsigned short* __restrict__ w2c,
                                                 float* __restrict__ bn) {
  const int tid = threadIdx.x;
  if (blockIdx.x >= NTIL) {
    const int pb = blockIdx.x - NTIL;
    const int gi = pb * 256 + tid;
    float4 v = *(const float4*)(x + (size_t)gi * 4);
    ushort4 o;
    o.x = f2bf(v.x); o.y = f2bf(v.y); o.z = f2bf(v.z); o.w = f2bf(v.w);
    *(ushort4*)(xb + (size_t)gi * 4) = o;
    if (pb < 64) {
      int i = pb * 256 + tid;  // 0..16383
      int oo = i >> 7, k = i & 127;
      float vv1 = (k < 64) ? w1l[oo * 64 + k] : w1r[oo * 64 + (k - 64)];
      w1c[i] = f2bf(vv1);
      float vv2 = (oo < 64) ? w2l[oo * 128 + k] : w2r[(oo - 64) * 128 + k];
      w2c[i] = f2bf(vv2);
      if (i < 128) {
        float sc = g1[i] * rsqrtf(v1[i] + EPSV);
        bn[i] = sc;
        bn[128 + i] = (b1l[i] - m1[i]) * sc + be1[i];
      }
      if (i < 64) {
        float sc = g2[i] * rsqrtf(v2[i] + EPSV);
        bn[256 + i] = sc;
        bn[320 + i] = (b2l[i] - m2[i]) * sc + be2[i];
      }
    }
    return;
  }
  __shared__ int cnt[NBUK];
  __shared__ int lo[NBUK];
  __shared__ int ts[256];
  __shared__ unsigned stage[TILE];
  const int t = blockIdx.x;
  const int e0 = t * TILE;
  const int m = min(TILE, NE - e0);

  int dreg[8], sreg[8];
#pragma unroll
  for (int u = 0; u < 8; ++u) {
    int i = u * 256 + tid;
    if (i < m) {
      dreg[u] = dst[e0 + i];
      sreg[u] = src[e0 + i];
    } else {
      dreg[u] = -1;
    }
  }

  for (int i = tid; i < NBUK; i += 256) cnt[i] = 0;
  __syncthreads();
#pragma unroll
  for (int u = 0; u < 8; ++u) {
    if (dreg[u] >= 0) atomicAdd(&cnt[dreg[u] >> 9], 1);
  }
  __syncthreads();
  int c = (tid < NBUK) ? cnt[tid] : 0;
  ts[tid] = c;
  __syncthreads();
  for (int d = 1; d < 256; d <<= 1) {
    int v = (tid >= d) ? ts[tid - d] : 0;
    __syncthreads();
    ts[tid] += v;
    __syncthreads();
  }
  if (tid < NBUK) {
    int ex = ts[tid] - c;
    lo[tid] = ex;
    cnt[tid] = ex;
  }
  __syncthreads();
#pragma unroll
  for (int u = 0; u < 8; ++u) {
    if (dreg[u] >= 0) {
      int pos = atomicAdd(&cnt[dreg[u] >> 9], 1);
      stage[pos] = ((unsigned)(dreg[u] & 511) << 17) | (unsigned)sreg[u];
    }
  }
  __syncthreads();
  for (int i = tid; i < m; i += 256) pairs[(size_t)t * TILE + i] = stage[i];
  if (tid < NBUK) {
    tileCnt[t * NBUK + tid] = cnt[tid] - lo[tid];
    tileLo[t * NBUK + tid] = lo[tid];
  }
}

// ---------------- phase 1.5: per-bucket prefix over tiles ----------------
__global__ __launch_bounds__(256) void k_colscan(const int* __restrict__ tileCnt,
                                                 int* __restrict__ colBase) {
  __shared__ int ts[256];
  const int tid = threadIdx.x;
  const int b = blockIdx.x;
  int v[4];
  int s = 0;
#pragma unroll
  for (int j = 0; j < 4; ++j) {
    int tt = tid * 4 + j;
    v[j] = (tt < NTIL) ? tileCnt[tt * NBUK + b] : 0;
    s += v[j];
  }
  ts[tid] = s;
  __syncthreads();
  for (int d = 1; d < 256; d <<= 1) {
    int x = (tid >= d) ? ts[tid - d] : 0;
    __syncthreads();
    ts[tid] += x;
    __syncthreads();
  }
  int run = ts[tid] - s;
#pragma unroll
  for (int j = 0; j < 4; ++j) {
    int tt = tid * 4 + j;
    if (tt < NTIL) colBase[(size_t)b * NTIL + tt] = run;
    run += v[j];
  }
}

// ---------------- phase 2: per-bucket CSR build via GATHER (self-computed bucketBase) ----------------
__global__ __launch_bounds__(512) void k_build(const unsigned* __restrict__ pairs,
                                               const int* __restrict__ tileCnt,
                                               const int* __restrict__ tileLo,
                                               const int* __restrict__ colBase,
                                               int* __restrict__ deg,
                                               int* __restrict__ offset,
                                               int* __restrict__ csr) {
  __shared__ unsigned stageA[CAP];
  __shared__ unsigned stageB[CAP];
  __shared__ int colB[NTIL];
  __shared__ int tLo[NTIL];
  __shared__ int hist[512];
  __shared__ int ts[512];
  __shared__ int obase_sh, count_sh;
  const int tid = threadIdx.x;
  const int b = blockIdx.x;
  const int nbase = b * 512;
  const int nloc = min(512, NN - nbase);

  int tb = 0;
  if (tid < NBUK) {
    int cb = colBase[(size_t)tid * NTIL + (NTIL - 1)];
    int tc = tileCnt[(NTIL - 1) * NBUK + tid];
    tb = min(cb + tc, CAP);
  }
  ts[tid] = tb;
  __syncthreads();
  for (int d = 1; d < 512; d <<= 1) {
    int v = (tid >= d) ? ts[tid - d] : 0;
    __syncthreads();
    ts[tid] += v;
    __syncthreads();
  }
  if (tid == b) { obase_sh = ts[tid] - tb; count_sh = tb; }
  for (int i = tid; i < NTIL; i += 512) {
    colB[i] = colBase[(size_t)b * NTIL + i];
    tLo[i] = tileLo[i * NBUK + b];
  }
  hist[tid] = 0;
  __syncthreads();
  const int obase = obase_sh;
  const int count = count_sh;

  for (int i = tid; i < count; i += 512) {
    int a = 0, z = NTIL - 1;
    while (a < z) {
      int mid = (a + z + 1) >> 1;
      if (colB[mid] <= i) a = mid; else z = mid - 1;
    }
    stageA[i] = pairs[(size_t)a * TILE + tLo[a] + (i - colB[a])];
  }
  __syncthreads();
  for (int i = tid; i < count; i += 512) {
    atomicAdd(&hist[stageA[i] >> 17], 1);
  }
  __syncthreads();
  int s = hist[tid];
  ts[tid] = s;
  __syncthreads();
  for (int d = 1; d < 512; d <<= 1) {
    int v = (tid >= d) ? ts[tid - d] : 0;
    __syncthreads();
    ts[tid] += v;
    __syncthreads();
  }
  int ex = ts[tid] - s;
  if (tid < nloc) {
    deg[nbase + tid] = s;
    offset[nbase + tid] = obase + ex;
  }
  hist[tid] = ex;
  __syncthreads();
  for (int i = tid; i < count; i += 512) {
    unsigned e = stageA[i];
    int pos = atomicAdd(&hist[e >> 17], 1);
    stageB[pos] = e & 0x1FFFFu;
  }
  __syncthreads();
  for (int i = tid; i < count; i += 512) csr[obase + i] = (int)stageB[i];
}

// ---------------- mean-aggregate: 8 lanes/node, 8-deep unrolled gather ----------------
__global__ __launch_bounds__(256) void k_aggregate(const unsigned short* __restrict__ xb,
                                                   const int* __restrict__ deg,
                                                   const int* __restrict__ offset,
                                                   const int* __restrict__ csr,
                                                   unsigned short* __restrict__ aggB) {
  int tid = threadIdx.x;
  int node = blockIdx.x * 32 + (tid >> 3);
  int j = tid & 7;
  int cnt = deg[node];
  const int* arow = csr + offset[node];
  float a0=0.f,a1=0.f,a2=0.f,a3=0.f,a4=0.f,a5=0.f,a6=0.f,a7=0.f;
  int k = 0;
  for (; k + 8 <= cnt; k += 8) {
    int s[8];
#pragma unroll
    for (int u = 0; u < 8; ++u) s[u] = arow[k + u];
    uint4 v[8];
#pragma unroll
    for (int u = 0; u < 8; ++u) v[u] = *(const uint4*)(xb + (size_t)s[u] * 64 + j * 8);
#pragma unroll
    for (int u = 0; u < 8; ++u) {
      a0 += bf2f(v[u].x & 0xffff); a1 += bf2f(v[u].x >> 16);
      a2 += bf2f(v[u].y & 0xffff); a3 += bf2f(v[u].y >> 16);
      a4 += bf2f(v[u].z & 0xffff); a5 += bf2f(v[u].z >> 16);
      a6 += bf2f(v[u].w & 0xffff); a7 += bf2f(v[u].w >> 16);
    }
  }
  if (k + 4 <= cnt) {
    int s[4];
#pragma unroll
    for (int u = 0; u < 4; ++u) s[u] = arow[k + u];
    uint4 v[4];
#pragma unroll
    for (int u = 0; u < 4; ++u) v[u] = *(const uint4*)(xb + (size_t)s[u] * 64 + j * 8);
#pragma unroll
    for (int u = 0; u < 4; ++u) {
      a0 += bf2f(v[u].x & 0xffff); a1 += bf2f(v[u].x >> 16);
      a2 += bf2f(v[u].y & 0xffff); a3 += bf2f(v[u].y >> 16);
      a4 += bf2f(v[u].z & 0xffff); a5 += bf2f(v[u].z >> 16);
      a6 += bf2f(v[u].w & 0xffff); a7 += bf2f(v[u].w >> 16);
    }
    k += 4;
  }
  for (; k < cnt; ++k) {
    int s = arow[k];
    uint4 v = *(const uint4*)(xb + (size_t)s * 64 + j * 8);
    a0 += bf2f(v.x & 0xffff); a1 += bf2f(v.x >> 16);
    a2 += bf2f(v.y & 0xffff); a3 += bf2f(v.y >> 16);
    a4 += bf2f(v.z & 0xffff); a5 += bf2f(v.z >> 16);
    a6 += bf2f(v.w & 0xffff); a7 += bf2f(v.w >> 16);
  }
  float inv = 1.0f / fmaxf((float)cnt, 1.0f);
  ushort4 r0, r1;
  r0.x = f2bf(a0 * inv); r0.y = f2bf(a1 * inv); r0.z = f2bf(a2 * inv); r0.w = f2bf(a3 * inv);
  r1.x = f2bf(a4 * inv); r1.y = f2bf(a5 * inv); r1.z = f2bf(a6 * inv); r1.w = f2bf(a7 * inv);
  *(ushort4*)(aggB + (size_t)node * 64 + j * 8) = r0;
  *(ushort4*)(aggB + (size_t)node * 64 + j * 8 + 4) = r1;
}

// ---------------- fused MFMA: weight-stationary, async staging, 1 barrier ----------------
__global__ __launch_bounds__(512, 1) void k_gemm12(const unsigned short* __restrict__ aggB,
                                                   const unsigned short* __restrict__ xb,
                                                   const unsigned short* __restrict__ w1c,
                                                   const unsigned short* __restrict__ w2c,
                                                   const float* __restrict__ bn,
                                                   unsigned short* __restrict__ t,
                                                   unsigned short* __restrict__ r2) {
  __shared__ unsigned short w1lds[32 * 512];      // 32KB fragment-major
  __shared__ unsigned short w2lds[32 * 512];      // 32KB fragment-major
  __shared__ unsigned short hlds[8][2][16 * 128]; // 64KB
  __shared__ float bnlds[384];                    // 1.5KB
  const int tid = threadIdx.x;
  const int w = tid >> 6;
  const int lane = tid & 63;
  const int lr = lane & 15;
  const int q = lane >> 4;
  const int tile = blockIdx.x * 8 + w;
  const int base = tile * 32;
  const int nA = base + lr, nB = base + 16 + lr;
  const int cA = min(nA, NN - 1), cB = min(nB, NN - 1);
  const int swz = (lr & 7) << 4;

#pragma unroll
  for (int it = 0; it < 4; ++it) {
    int idx = it * 512 + tid;
    int f = idx >> 6, l = idx & 63;
    int gofs = ((f >> 2) * 16 + (l & 15)) * 128 + (f & 3) * 32 + (l >> 4) * 8;
    gload_lds16(w1c + gofs, &w1lds[(it * 512 + w * 64) * 8]);
    gload_lds16(w2c + gofs, &w2lds[(it * 512 + w * 64) * 8]);
  }
  if (tid < 384) bnlds[tid] = bn[tid];

  bf16x8 fA[4], fB[4];
  {
    const unsigned short* a = aggB + (size_t)cA * 64 + q * 8;
    const unsigned short* xx = xb + (size_t)cA * 64 + q * 8;
    fA[0] = *(const bf16x8*)a;        fA[1] = *(const bf16x8*)(a + 32);
    fA[2] = *(const bf16x8*)xx;       fA[3] = *(const bf16x8*)(xx + 32);
  }
  {
    const unsigned short* a = aggB + (size_t)cB * 64 + q * 8;
    const unsigned short* xx = xb + (size_t)cB * 64 + q * 8;
    fB[0] = *(const bf16x8*)a;        fB[1] = *(const bf16x8*)(a + 32);
    fB[2] = *(const bf16x8*)xx;       fB[3] = *(const bf16x8*)(xx + 32);
  }
  __syncthreads();
  if (base >= NN) return;

  char* ldsA = (char*)&hlds[w][0][0];
  char* ldsB = (char*)&hlds[w][1][0];

#pragma unroll
  for (int ot = 0; ot < 8; ++ot) {
    const unsigned short* wp = &w1lds[(ot * 4) * 512 + lane * 8];
    bf16x8 w0 = *(const bf16x8*)(wp);
    bf16x8 w1 = *(const bf16x8*)(wp + 512);
    bf16x8 w2 = *(const bf16x8*)(wp + 1024);
    bf16x8 w3 = *(const bf16x8*)(wp + 1536);
    f32x4 aA = {0.f, 0.f, 0.f, 0.f}, aB = {0.f, 0.f, 0.f, 0.f};
    aA = __builtin_amdgcn_mfma_f32_16x16x32_bf16(w0, fA[0], aA, 0, 0, 0);
    aA = __builtin_amdgcn_mfma_f32_16x16x32_bf16(w1, fA[1], aA, 0, 0, 0);
    aA = __builtin_amdgcn_mfma_f32_16x16x32_bf16(w2, fA[2], aA, 0, 0, 0);
    aA = __builtin_amdgcn_mfma_f32_16x16x32_bf16(w3, fA[3], aA, 0, 0, 0);
    aB = __builtin_amdgcn_mfma_f32_16x16x32_bf16(w0, fB[0], aB, 0, 0, 0);
    aB = __builtin_amdgcn_mfma_f32_16x16x32_bf16(w1, fB[1], aB, 0, 0, 0);
    aB = __builtin_amdgcn_mfma_f32_16x16x32_bf16(w2, fB[2], aB, 0, 0, 0);
    aB = __builtin_amdgcn_mfma_f32_16x16x32_bf16(w3, fB[3], aB, 0, 0, 0);
    const int o = ot * 16 + q * 4;
    float4 sc = *(const float4*)&bnlds[o];
    float4 sh = *(const float4*)&bnlds[128 + o];
    ushort4 hA, hB;
    hA.x = f2bf(fmaxf(aA[0] * sc.x + sh.x, 0.f));
    hA.y = f2bf(fmaxf(aA[1] * sc.y + sh.y, 0.f));
    hA.z = f2bf(fmaxf(aA[2] * sc.z + sh.z, 0.f));
    hA.w = f2bf(fmaxf(aA[3] * sc.w + sh.w, 0.f));
    hB.x = f2bf(fmaxf(aB[0] * sc.x + sh.x, 0.f));
    hB.y = f2bf(fmaxf(aB[1] * sc.y + sh.y, 0.f));
    hB.z = f2bf(fmaxf(aB[2] * sc.z + sh.z, 0.f));
    hB.w = f2bf(fmaxf(aB[3] * sc.w + sh.w, 0.f));
    const int wb = lr * 256 + ot * 32 + q * 8;
    *(ushort4*)(ldsA + (wb ^ swz)) = hA;
    *(ushort4*)(ldsB + (wb ^ swz)) = hB;
  }

  bf16x8 hA[4], hB[4];
#pragma unroll
  for (int jj = 0; jj < 4; ++jj) {
    const int rb = lr * 256 + jj * 64 + q * 16;
    hA[jj] = *(const bf16x8*)(ldsA + (rb ^ swz));
    hB[jj] = *(const bf16x8*)(ldsB + (rb ^ swz));
  }

#pragma unroll
  for (int ot = 0; ot < 8; ++ot) {
    const unsigned short* wp = &w2lds[(ot * 4) * 512 + lane * 8];
    bf16x8 w0 = *(const bf16x8*)(wp);
    bf16x8 w1 = *(const bf16x8*)(wp + 512);
    bf16x8 w2 = *(const bf16x8*)(wp + 1024);
    bf16x8 w3 = *(const bf16x8*)(wp + 1536);
    f32x4 aA = {0.f, 0.f, 0.f, 0.f}, aB = {0.f, 0.f, 0.f, 0.f};
    aA = __builtin_amdgcn_mfma_f32_16x16x32_bf16(w0, hA[0], aA, 0, 0, 0);
    aA = __builtin_amdgcn_mfma_f32_16x16x32_bf16(w1, hA[1], aA, 0, 0, 0);
    aA = __builtin_amdgcn_mfma_f32_16x16x32_bf16(w2, hA[2], aA, 0, 0, 0);
    aA = __builtin_amdgcn_mfma_f32_16x16x32_bf16(w3, hA[3], aA, 0, 0, 0);
    aB = __builtin_amdgcn_mfma_f32_16x16x32_bf16(w0, hB[0], aB, 0, 0, 0);
    aB = __builtin_amdgcn_mfma_f32_16x16x32_bf16(w1, hB[1], aB, 0, 0, 0);
    aB = __builtin_amdgcn_mfma_f32_16x16x32_bf16(w2, hB[2], aB, 0, 0, 0);
    aB = __builtin_amdgcn_mfma_f32_16x16x32_bf16(w3, hB[3], aB, 0, 0, 0);
    ushort4 tv;
    if (ot < 4) {
      const int o = ot * 16 + q * 4;
      tv.x = f2bf(aA[0]); tv.y = f2bf(aA[1]); tv.z = f2bf(aA[2]); tv.w = f2bf(aA[3]);
      if (nA < NN) *(ushort4*)(t + (size_t)nA * 64 + o) = tv;
      tv.x = f2bf(aB[0]); tv.y = f2bf(aB[1]); tv.z = f2bf(aB[2]); tv.w = f2bf(aB[3]);
      if (nB < NN) *(ushort4*)(t + (size_t)nB * 64 + o) = tv;
    } else {
      const int o = (ot - 4) * 16 + q * 4;
      tv.x = f2bf(aA[0]); tv.y = f2bf(aA[1]); tv.z = f2bf(aA[2]); tv.w = f2bf(aA[3]);
      if (nA < NN) *(ushort4*)(r2 + (size_t)nA * 64 + o) = tv;
      tv.x = f2bf(aB[0]); tv.y = f2bf(aB[1]); tv.z = f2bf(aB[2]); tv.w = f2bf(aB[3]);
      if (nB < NN) *(ushort4*)(r2 + (size_t)nB * 64 + o) = tv;
    }
  }
}

// ---------------- layer2 aggregate + BN2: 8 lanes/node, 8-deep unrolled gather ----------------
__global__ __launch_bounds__(256) void k_agg2fin(const unsigned short* __restrict__ t,
                                                 const int* __restrict__ deg,
                                                 const int* __restrict__ offset,
                                                 const int* __restrict__ csr,
                                                 const unsigned short* __restrict__ r2,
                                                 const float* __restrict__ bn,
                                                 float* __restrict__ outp) {
  int tid = threadIdx.x;
  int node = blockIdx.x * 32 + (tid >> 3);
  int j = tid & 7;
  int cnt = deg[node];
  const int* arow = csr + offset[node];
  float a0=0.f,a1=0.f,a2=0.f,a3=0.f,a4=0.f,a5=0.f,a6=0.f,a7=0.f;
  int k = 0;
  for (; k + 8 <= cnt; k += 8) {
    int s[8];
#pragma unroll
    for (int u = 0; u < 8; ++u) s[u] = arow[k + u];
    uint4 v[8];
#pragma unroll
    for (int u = 0; u < 8; ++u) v[u] = *(const uint4*)(t + (size_t)s[u] * 64 + j * 8);
#pragma unroll
    for (int u = 0; u < 8; ++u) {
      a0 += bf2f(v[u].x & 0xffff); a1 += bf2f(v[u].x >> 16);
      a2 += bf2f(v[u].y & 0xffff); a3 += bf2f(v[u].y >> 16);
      a4 += bf2f(v[u].z & 0xffff); a5 += bf2f(v[u].z >> 16);
      a6 += bf2f(v[u].w & 0xffff); a7 += bf2f(v[u].w >> 16);
    }
  }
  if (k + 4 <= cnt) {
    int s[4];
#pragma unroll
    for (int u = 0; u < 4; ++u) s[u] = arow[k + u];
    uint4 v[4];
#pragma unroll
    for (int u = 0; u < 4; ++u) v[u] = *(const uint4*)(t + (size_t)s[u] * 64 + j * 8);
#pragma unroll
    for (int u = 0; u < 4; ++u) {
      a0 += bf2f(v[u].x & 0xffff); a1 += bf2f(v[u].x >> 16);
      a2 += bf2f(v[u].y & 0xffff); a3 += bf2f(v[u].y >> 16);
      a4 += bf2f(v[u].z & 0xffff); a5 += bf2f(v[u].z >> 16);
      a6 += bf2f(v[u].w & 0xffff); a7 += bf2f(v[u].w >> 16);
    }
    k += 4;
  }
  for (; k < cnt; ++k) {
    int s = arow[k];
    uint4 v = *(const uint4*)(t + (size_t)s * 64 + j * 8);
    a0 += bf2f(v.x & 0xffff); a1 += bf2f(v.x >> 16);
    a2 += bf2f(v.y & 0xffff); a3 += bf2f(v.y >> 16);
    a4 += bf2f(v.z & 0xffff); a5 += bf2f(v.z >> 16);
    a6 += bf2f(v.w & 0xffff); a7 += bf2f(v.w >> 16);
  }
  float inv = 1.0f / fmaxf((float)cnt, 1.0f);
  int o = j * 8;
  uint4 rv = *(const uint4*)(r2 + (size_t)node * 64 + o);
  float r0 = bf2f(rv.x & 0xffff), r1 = bf2f(rv.x >> 16);
  float r2a = bf2f(rv.y & 0xffff), r3 = bf2f(rv.y >> 16);
  float r4 = bf2f(rv.z & 0xffff), r5 = bf2f(rv.z >> 16);
  float r6 = bf2f(rv.w & 0xffff), r7 = bf2f(rv.w >> 16);
  float4 sca = *(const float4*)(bn + 256 + o);
  float4 scb = *(const float4*)(bn + 256 + o + 4);
  float4 sha = *(const float4*)(bn + 320 + o);
  float4 shb = *(const float4*)(bn + 320 + o + 4);
  float4 o0, o1;
  o0.x = (a0 * inv + r0) * sca.x + sha.x;
  o0.y = (a1 * inv + r1) * sca.y + sha.y;
  o0.z = (a2 * inv + r2a) * sca.z + sha.z;
  o0.w = (a3 * inv + r3) * sca.w + sha.w;
  o1.x = (a4 * inv + r4) * scb.x + shb.x;
  o1.y = (a5 * inv + r5) * scb.y + shb.y;
  o1.z = (a6 * inv + r6) * scb.z + shb.z;
  o1.w = (a7 * inv + r7) * scb.w + shb.w;
  *(float4*)(outp + (size_t)node * 64 + o) = o0;
  *(float4*)(outp + (size_t)node * 64 + o + 4) = o1;
}

extern "C" void kernel_launch(void* const* d_in, const int* in_sizes, int n_in,
                              void* d_out, int out_size, void* d_ws, size_t ws_size,
                              hipStream_t stream) {
  const float* x   = (const float*)d_in[0];
  const int*   ei  = (const int*)d_in[1];
  const float* w1l = (const float*)d_in[2];
  const float* b1l = (const float*)d_in[3];
  const float* w1r = (const float*)d_in[4];
  const float* g1  = (const float*)d_in[5];
  const float* be1 = (const float*)d_in[6];
  const float* m1  = (const float*)d_in[7];
  const float* v1  = (const float*)d_in[8];
  const float* w2l = (const float*)d_in[9];
  const float* b2l = (const float*)d_in[10];
  const float* w2r = (const float*)d_in[11];
  const float* g2  = (const float*)d_in[12];
  const float* be2 = (const float*)d_in[13];
  const float* m2  = (const float*)d_in[14];
  const float* v2  = (const float*)d_in[15];
  float* outp = (float*)d_out;

  char* ws = (char*)d_ws;
  // layout (bytes), 16B-aligned:
  //           0 : tileCnt    (613,120)     [782][196]
  //     613,120 : tileLo     (613,120)     [782][196]
  //   1,226,240 : colBase    (613,120)     [196][782]
  //   1,839,360 : deg        (400,000)     -> 2,239,360
  //   2,239,360 : offset     (400,000)     -> 2,639,360
  //   2,639,360 : pairs      (6,406,144)   -> 9,045,504   (tile-major)
  //   9,045,504 : csr        (6,400,000)   -> 15,445,504
  //  15,445,504 : w1c bf16   (32,768)      -> 15,478,272
  //  15,478,272 : w2c bf16   (32,768)      -> 15,511,040
  //  15,511,040 : bn  fp32   (2,048)       -> 15,513,088
  //  15,513,088 : xb  bf16   (12,800,000)  -> 28,313,088
  //  28,313,088 : aggB bf16  (12,800,000)  -> 41,113,088
  //  41,113,088 : t   bf16   (12,800,000)  -> 53,913,088
  //  53,913,088 : r2  bf16   (12,800,000)  -> 66,713,088  (~67 MB)
  int*            tileCnt = (int*)ws;
  int*            tileLo  = (int*)(ws + 613120);
  int*            colBase = (int*)(ws + 1226240);
  int*            deg     = (int*)(ws + 1839360);
  int*            offset  = (int*)(ws + 2239360);
  unsigned*       pairs   = (unsigned*)(ws + 2639360);
  int*            csr     = (int*)(ws + 9045504);
  unsigned short* w1c     = (unsigned short*)(ws + 15445504);
  unsigned short* w2c     = (unsigned short*)(ws + 15478272);
  float*          bn      = (float*)(ws + 15511040);
  unsigned short* xb      = (unsigned short*)(ws + 15513088);
  unsigned short* aggB    = (unsigned short*)(ws + 28313088);
  unsigned short* t       = (unsigned short*)(ws + 41113088);
  unsigned short* r2      = (unsigned short*)(ws + 53913088);

  const int* srcp = ei;
  const int* dstp = ei + NE;

  hipLaunchKernelGGL(k_binprep, dim3(NTIL + NPREP), dim3(256), 0, stream,
                     srcp, dstp, pairs, tileCnt, tileLo,
                     x, xb, w1l, w1r, w2l, w2r, b1l, g1, be1, m1, v1,
                     b2l, g2, be2, m2, v2, w1c, w2c, bn);
  hipLaunchKernelGGL(k_colscan, dim3(NBUK), dim3(256), 0, stream,
                     tileCnt, colBase);
  hipLaunchKernelGGL(k_build, dim3(NBUK), dim3(512), 0, stream,
                     pairs, tileCnt, tileLo, colBase, deg, offset, csr);
  hipLaunchKernelGGL(k_aggregate, dim3(NN / 32), dim3(256), 0, stream,
                     xb, deg, offset, csr, aggB);
  hipLaunchKernelGGL(k_gemm12, dim3((NN / 32 + 7) / 8), dim3(512), 0, stream,
                     aggB, xb, w1c, w2c, bn, t, r2);
  hipLaunchKernelGGL(k_agg2fin, dim3(NN / 32), dim3(256), 0, stream,
                     t, deg, offset, csr, r2, bn, outp);
}